// Round 12
// baseline (166.870 us; speedup 1.0000x reference)
//
#include <hip/hip_runtime.h>

// Model_47510928228872: 2-layer bidirectional LSTM (H=3) + linear + sigmoid.
// B=8192, T=512, fp32.
//
// Round 12: phase split with TWO INDEPENDENT gate-split wave streams/SIMD.
//  K1: l0-fwd (waves 0..1023) + l0-bwd (waves 1024..2047) in one launch,
//      8 lanes/batch gate-split cell (proven 52us/direction at 1 wave/SIMD),
//      2048 waves = 2/SIMD -> independent waves fill each other's dependency
//      stalls (unlike round 6, per-wave work is NOT doubled).
//  K2: l1-fwd + 1-step l1-bwd + linear head (round-11 KB verbatim, ~50us).
// y0f/y0b layout [B][64 blk][3 j][8 s], slot t = h(t) (unshifted).

#define B_ 8192
#define T_ 512
#define LOG2E 1.4426950408889634f

typedef float v2f __attribute__((ext_vector_type(2)));

__device__ __forceinline__ float rcp_(float x)  { return __builtin_amdgcn_rcpf(x); }
__device__ __forceinline__ float exp2_(float x) { return __builtin_amdgcn_exp2f(x); }
__device__ __forceinline__ float sigm_(float x) {
  return rcp_(1.0f + exp2_(-LOG2E * x));
}
__device__ __forceinline__ float tanh_(float x) {
  return 1.0f - 2.0f * rcp_(1.0f + exp2_(2.0f * LOG2E * x));
}
__device__ __forceinline__ float act_(float p) { return rcp_(1.f + exp2_(p)); }

__device__ __forceinline__ v2f sp(float s) { return (v2f){s, s}; }
__device__ __forceinline__ v2f pkfma(v2f a, float b, v2f c) {
  return __builtin_elementwise_fma(a, sp(b), c);
}

#define PIN2(v) do {                                                      \
    double _d = __builtin_bit_cast(double, v);                            \
    asm volatile("" : "+v"(_d));                                          \
    v = __builtin_bit_cast(v2f, _d); } while (0)

template <int CTRL>
__device__ __forceinline__ float dppf(float v) {
  int s = __float_as_int(v);
  return __int_as_float(__builtin_amdgcn_update_dpp(s, s, CTRL, 0xF, 0xF, false));
}
#define QP0 dppf<0x00>
#define QP1 dppf<0x55>
#define QP2 dppf<0xAA>
#define SHL4 0x104
#define SHR4 0x114

// ============ Kernel 1: layer-0, one direction per wave (gate-split) ========
template <bool DIRB>
__device__ __forceinline__ void l0_dir(
    const float* __restrict__ x,
    const float* __restrict__ Wi, const float* __restrict__ Wh,
    const float* __restrict__ bi, const float* __restrict__ bh,
    float* __restrict__ yout, int b, int lane)
{
  bool qgo = (lane & 4) != 0;           // quad role: (i,f) vs (g,o)
  int j = lane & 3; int jj = (j < 3) ? j : 0;
  const int ra = (qgo ? 6 : 0) + jj, rb = ra + 3;
  const float kx = qgo ? (-2.f * LOG2E) : (-LOG2E);
  const float ky = -LOG2E;
  const float avx = qgo ? 2.f : 1.f;
  const float dvx = qgo ? -1.f : 0.f;

  v2f w0 = {Wi[ra*3+0]*kx, Wi[rb*3+0]*ky},
      w1 = {Wi[ra*3+1]*kx, Wi[rb*3+1]*ky},
      w2 = {Wi[ra*3+2]*kx, Wi[rb*3+2]*ky};
  v2f u0 = {Wh[ra*3+0]*kx, Wh[rb*3+0]*ky},
      u1 = {Wh[ra*3+1]*kx, Wh[rb*3+1]*ky},
      u2 = {Wh[ra*3+2]*kx, Wh[rb*3+2]*ky};
  v2f b2 = {(bi[ra]+bh[ra])*kx, (bi[rb]+bh[rb])*ky};

  float h = 0.f, c = 0.f, ha0 = 0.f, ha1 = 0.f, ha2 = 0.f;
  float hs0, hs1, hs2, hs3, hs4, hs5, hs6, hs7;

  const float4* xq = (const float4*)(x + (size_t)b * (T_ * 3));
  float* ywb = yout + (size_t)b * (T_ * 3) + jj * 8;

  float4 p0, p1, p2, p3, p4, p5, q0, q1, q2, q3, q4, q5;

#define LD1(blk, R0, R1, R2, R3, R4, R5) do {                             \
    const float4* _p = xq + (blk) * 6;                                    \
    R0 = _p[0]; R1 = _p[1]; R2 = _p[2];                                   \
    R3 = _p[3]; R4 = _p[4]; R5 = _p[5];                                   \
    __builtin_amdgcn_sched_barrier(0); } while (0)

#define STEP1(x0, x1, x2, HOUT) do {                                      \
    v2f pv = pkfma(w0, (x0), b2); pv = pkfma(w1, (x1), pv);               \
    pv = pkfma(w2, (x2), pv);                                             \
    v2f uv = u0 * sp(ha0); uv = pkfma(u1, ha1, uv);                       \
    uv = pkfma(u2, ha2, uv);                                              \
    pv = pv + uv;                                                         \
    float r0v = act_(pv.x);                                               \
    float ayv = act_(pv.y);            /* f (q0) or o (q1) */             \
    float axv = __builtin_fmaf(avx, r0v, dvx); /* i (q0) / tanh g (q1) */ \
    float slx = dppf<SHL4>(axv), sly = dppf<SHL4>(ayv);                   \
    float srx = dppf<SHR4>(axv), sry = dppf<SHR4>(ayv);                   \
    float pig = axv * (qgo ? srx : slx);   /* i*g on both quads */        \
    float gf  = qgo ? sry : ayv;                                          \
    float gO  = qgo ? ayv : sly;                                          \
    c = __builtin_fmaf(gf, c, pig);                                       \
    float th = __builtin_fmaf(                                            \
        2.f, rcp_(1.f + exp2_(-2.f * LOG2E * c)), -1.f);                  \
    h = gO * th;                                                          \
    ha0 = QP0(h); ha1 = QP1(h); ha2 = QP2(h);                             \
    HOUT = h; } while (0)

  // step s of a block uses dwords 3s..3s+2; hs slot s = h(t = blk*8+s)
#define S0(R0,R1,R2,R3,R4,R5) STEP1(R0.x, R0.y, R0.z, hs0)
#define S1(R0,R1,R2,R3,R4,R5) STEP1(R0.w, R1.x, R1.y, hs1)
#define S2(R0,R1,R2,R3,R4,R5) STEP1(R1.z, R1.w, R2.x, hs2)
#define S3(R0,R1,R2,R3,R4,R5) STEP1(R2.y, R2.z, R2.w, hs3)
#define S4(R0,R1,R2,R3,R4,R5) STEP1(R3.x, R3.y, R3.z, hs4)
#define S5(R0,R1,R2,R3,R4,R5) STEP1(R3.w, R4.x, R4.y, hs5)
#define S6(R0,R1,R2,R3,R4,R5) STEP1(R4.z, R4.w, R5.x, hs6)
#define S7(R0,R1,R2,R3,R4,R5) STEP1(R5.y, R5.z, R5.w, hs7)

  // fwd: t ascending (S0..S7); bwd: t descending (S7..S0). Slots unshifted.
#define PROC1(R0,R1,R2,R3,R4,R5) do {                                     \
    if (DIRB) {                                                           \
      S7(R0,R1,R2,R3,R4,R5); S6(R0,R1,R2,R3,R4,R5);                       \
      S5(R0,R1,R2,R3,R4,R5); S4(R0,R1,R2,R3,R4,R5);                       \
      S3(R0,R1,R2,R3,R4,R5); S2(R0,R1,R2,R3,R4,R5);                       \
      S1(R0,R1,R2,R3,R4,R5); S0(R0,R1,R2,R3,R4,R5);                       \
    } else {                                                              \
      S0(R0,R1,R2,R3,R4,R5); S1(R0,R1,R2,R3,R4,R5);                       \
      S2(R0,R1,R2,R3,R4,R5); S3(R0,R1,R2,R3,R4,R5);                       \
      S4(R0,R1,R2,R3,R4,R5); S5(R0,R1,R2,R3,R4,R5);                       \
      S6(R0,R1,R2,R3,R4,R5); S7(R0,R1,R2,R3,R4,R5);                       \
    } } while (0)

#define FLUSH1(blk) do {                                                  \
    if (lane < 3) {                                                       \
      float4* _o = (float4*)(ywb + (blk) * 24);                           \
      _o[0] = make_float4(hs0, hs1, hs2, hs3);                            \
      _o[1] = make_float4(hs4, hs5, hs6, hs7);                            \
    } } while (0)

#define BLK(k) (DIRB ? (63 - (k)) : (k))

  LD1(BLK(0), p0, p1, p2, p3, p4, p5);
  LD1(BLK(1), q0, q1, q2, q3, q4, q5);
  for (int k = 0; k < 64; k += 2) {
    PROC1(p0, p1, p2, p3, p4, p5);
    FLUSH1(BLK(k));
    if (k + 2 < 64) LD1(BLK(k + 2), p0, p1, p2, p3, p4, p5);
    PROC1(q0, q1, q2, q3, q4, q5);
    FLUSH1(BLK(k + 1));
    if (k + 3 < 64) LD1(BLK(k + 3), q0, q1, q2, q3, q4, q5);
  }
#undef LD1
#undef STEP1
#undef S0
#undef S1
#undef S2
#undef S3
#undef S4
#undef S5
#undef S6
#undef S7
#undef PROC1
#undef FLUSH1
#undef BLK
}

__global__ __launch_bounds__(256, 2) void lstm_l0_pair(
    const float* __restrict__ x,
    const float* __restrict__ Wf_ih, const float* __restrict__ Wf_hh,
    const float* __restrict__ bf_ih, const float* __restrict__ bf_hh,
    const float* __restrict__ Wr_ih, const float* __restrict__ Wr_hh,
    const float* __restrict__ br_ih, const float* __restrict__ br_hh,
    float* __restrict__ y0f, float* __restrict__ y0b)
{
  int gid = blockIdx.x * 256 + threadIdx.x;
  const int nfwd = B_ * 8;             // multiple of 256 -> wave-uniform split
  if (gid < nfwd) {
    l0_dir<false>(x, Wf_ih, Wf_hh, bf_ih, bf_hh, y0f, gid >> 3, gid & 7);
  } else {
    int g2 = gid - nfwd;
    l0_dir<true>(x, Wr_ih, Wr_hh, br_ih, br_hh, y0b, g2 >> 3, g2 & 7);
  }
}

// ======= Kernel 2: layer-1 fwd + epilogue (round-11 KB verbatim) ============
#define CELL_TAIL(HOUT)                                                   \
    float r0v = act_(pv.x);                                               \
    float ayv = act_(pv.y);                                               \
    float axv = __builtin_fmaf(avx, r0v, dvx);                            \
    float slx = dppf<SHL4>(axv), sly = dppf<SHL4>(ayv);                   \
    float srx = dppf<SHR4>(axv), sry = dppf<SHR4>(ayv);                   \
    float pig = axv * (qgo ? srx : slx);                                  \
    float gf  = qgo ? sry : ayv;                                          \
    float gO  = qgo ? ayv : sly;                                          \
    c = __builtin_fmaf(gf, c, pig);                                       \
    float th = __builtin_fmaf(                                            \
        2.f, rcp_(1.f + exp2_(-2.f * LOG2E * c)), -1.f);                  \
    h = gO * th;                                                          \
    ha0 = QP0(h); ha1 = QP1(h); ha2 = QP2(h);                             \
    HOUT = h;

__global__ __launch_bounds__(256) void lstm_l1_fwd(
    const float* __restrict__ Wih1, const float* __restrict__ Whh1,
    const float* __restrict__ bih1, const float* __restrict__ bhh1,
    const float* __restrict__ Wih1r,
    const float* __restrict__ bih1r, const float* __restrict__ bhh1r,
    const float* __restrict__ Wlin, const float* __restrict__ blin,
    const float* __restrict__ y0f, const float* __restrict__ y0b,
    float* __restrict__ out)
{
  int tid  = blockIdx.x * 256 + threadIdx.x;
  int b    = tid >> 3;
  int lane = tid & 7;
  bool qgo = (lane & 4) != 0;
  int j = lane & 3; int jj = (j < 3) ? j : 0;
  const int ra = (qgo ? 6 : 0) + jj, rb = ra + 3;
  const float kx = qgo ? (-2.f * LOG2E) : (-LOG2E);
  const float ky = -LOG2E;
  const float avx = qgo ? 2.f : 1.f;
  const float dvx = qgo ? -1.f : 0.f;

  v2f w0 = {Wih1[ra*6+0]*kx, Wih1[rb*6+0]*ky},
      w1 = {Wih1[ra*6+1]*kx, Wih1[rb*6+1]*ky},
      w2 = {Wih1[ra*6+2]*kx, Wih1[rb*6+2]*ky},
      w3 = {Wih1[ra*6+3]*kx, Wih1[rb*6+3]*ky},
      w4 = {Wih1[ra*6+4]*kx, Wih1[rb*6+4]*ky},
      w5 = {Wih1[ra*6+5]*kx, Wih1[rb*6+5]*ky};
  v2f u0 = {Whh1[ra*3+0]*kx, Whh1[rb*3+0]*ky},
      u1 = {Whh1[ra*3+1]*kx, Whh1[rb*3+1]*ky},
      u2 = {Whh1[ra*3+2]*kx, Whh1[rb*3+2]*ky};
  v2f b2 = {(bih1[ra]+bhh1[ra])*kx, (bih1[rb]+bhh1[rb])*ky};
  PIN2(w0); PIN2(w1); PIN2(w2); PIN2(w3); PIN2(w4); PIN2(w5);
  PIN2(u0); PIN2(u1); PIN2(u2); PIN2(b2);

  const float4* yfq = (const float4*)(y0f + (size_t)b * (T_ * 3));
  const float4* ybq = (const float4*)(y0b + (size_t)b * (T_ * 3));

  const float* ufp = y0f + (size_t)b * (T_ * 3) + 63 * 24 + 7;
  const float* ubp = y0b + (size_t)b * (T_ * 3) + 63 * 24 + 7;

  float h = 0.f, c = 0.f, ha0 = 0.f, ha1 = 0.f, ha2 = 0.f;
  float hs0, hs1, hs2, hs3, hs4, hs5, hs6, hs7;
  float4 pf0, pf1, pf2, pf3, pf4, pf5, pb0, pb1, pb2, pb3, pb4, pb5;
  float4 qf0, qf1, qf2, qf3, qf4, qf5, qb0, qb1, qb2, qb3, qb4, qb5;

#define LDB(blk, F0,F1,F2,F3,F4,F5, G0,G1,G2,G3,G4,G5) do {               \
    const float4* _f = yfq + (blk) * 6;                                   \
    const float4* _g = ybq + (blk) * 6;                                   \
    F0 = _f[0]; F1 = _f[1]; F2 = _f[2];                                   \
    F3 = _f[3]; F4 = _f[4]; F5 = _f[5];                                   \
    G0 = _g[0]; G1 = _g[1]; G2 = _g[2];                                   \
    G3 = _g[3]; G4 = _g[4]; G5 = _g[5];                                   \
    __builtin_amdgcn_sched_barrier(0); } while (0)

#define STEPB(f0, f1, f2, g0, g1, g2, HOUT) do {                          \
    v2f pv = pkfma(w0, (f0), b2); pv = pkfma(w1, (f1), pv);               \
    pv = pkfma(w2, (f2), pv);                                             \
    v2f nv = w3 * sp(g0); nv = pkfma(w4, (g1), nv);                       \
    nv = pkfma(w5, (g2), nv);                                             \
    v2f uv = u0 * sp(ha0); uv = pkfma(u1, ha1, uv);                       \
    uv = pkfma(u2, ha2, uv);                                              \
    pv = (pv + nv) + uv;                                                  \
    CELL_TAIL(HOUT) } while (0)

#define PROCB(F0,F1,F2,F3,F4,F5, G0,G1,G2,G3,G4,G5) do {                  \
    STEPB(F0.x, F2.x, F4.x,  G0.x, G2.x, G4.x, hs0);                      \
    STEPB(F0.y, F2.y, F4.y,  G0.y, G2.y, G4.y, hs1);                      \
    STEPB(F0.z, F2.z, F4.z,  G0.z, G2.z, G4.z, hs2);                      \
    STEPB(F0.w, F2.w, F4.w,  G0.w, G2.w, G4.w, hs3);                      \
    STEPB(F1.x, F3.x, F5.x,  G1.x, G3.x, G5.x, hs4);                      \
    STEPB(F1.y, F3.y, F5.y,  G1.y, G3.y, G5.y, hs5);                      \
    STEPB(F1.z, F3.z, F5.z,  G1.z, G3.z, G5.z, hs6);                      \
    STEPB(F1.w, F3.w, F5.w,  G1.w, G3.w, G5.w, hs7); } while (0)

  LDB(0, pf0,pf1,pf2,pf3,pf4,pf5, pb0,pb1,pb2,pb3,pb4,pb5);
  LDB(1, qf0,qf1,qf2,qf3,qf4,qf5, qb0,qb1,qb2,qb3,qb4,qb5);
  for (int it = 0; it < 32; ++it) {
    PROCB(pf0,pf1,pf2,pf3,pf4,pf5, pb0,pb1,pb2,pb3,pb4,pb5);
    if (it < 31) LDB(2*it+2, pf0,pf1,pf2,pf3,pf4,pf5, pb0,pb1,pb2,pb3,pb4,pb5);
    PROCB(qf0,qf1,qf2,qf3,qf4,qf5, qb0,qb1,qb2,qb3,qb4,qb5);
    if (it < 31) LDB(2*it+3, qf0,qf1,qf2,qf3,qf4,qf5, qb0,qb1,qb2,qb3,qb4,qb5);
  }
  (void)hs0; (void)hs1; (void)hs2; (void)hs3;
  (void)hs4; (void)hs5; (void)hs6; (void)hs7;

  float uf0 = ufp[0], uf1 = ufp[8], uf2 = ufp[16];
  float ub0 = ubp[0], ub1 = ubp[8], ub2 = ubp[16];

  float h1b;
  {
    v2f r0 = {Wih1r[ra*6+0]*kx, Wih1r[rb*6+0]*ky},
        r1 = {Wih1r[ra*6+1]*kx, Wih1r[rb*6+1]*ky},
        r2 = {Wih1r[ra*6+2]*kx, Wih1r[rb*6+2]*ky},
        r3 = {Wih1r[ra*6+3]*kx, Wih1r[rb*6+3]*ky},
        r4 = {Wih1r[ra*6+4]*kx, Wih1r[rb*6+4]*ky},
        r5 = {Wih1r[ra*6+5]*kx, Wih1r[rb*6+5]*ky};
    v2f br = {(bih1r[ra]+bhh1r[ra])*kx, (bih1r[rb]+bhh1r[rb])*ky};
    v2f qv = pkfma(r0, uf0, br); qv = pkfma(r1, uf1, qv);
    qv = pkfma(r2, uf2, qv);     qv = pkfma(r3, ub0, qv);
    qv = pkfma(r4, ub1, qv);     qv = pkfma(r5, ub2, qv);
    float r0v = act_(qv.x);
    float ayv = act_(qv.y);
    float axv = __builtin_fmaf(avx, r0v, dvx);
    float slx = dppf<SHL4>(axv), sly = dppf<SHL4>(ayv);
    float srx = dppf<SHR4>(axv);
    float gi = qgo ? srx : axv;
    float gG = qgo ? axv : slx;
    float gO = qgo ? ayv : sly;
    float cb = gi * gG;
    h1b = gO * tanh_(cb);
  }

  float part = 0.f;
  if (!qgo && j < 3) part = __builtin_fmaf(Wlin[j], h, Wlin[3 + j] * h1b);
  part += __shfl_xor(part, 1, 8);
  part += __shfl_xor(part, 2, 8);
  part += __shfl_xor(part, 4, 8);
  if (lane == 0) out[b] = sigm_(part + blin[0]);
#undef LDB
#undef STEPB
#undef PROCB
}

extern "C" void kernel_launch(void* const* d_in, const int* in_sizes, int n_in,
                              void* d_out, int out_size, void* d_ws, size_t ws_size,
                              hipStream_t stream) {
  const float* x        = (const float*)d_in[0];
  const float* W_ih_l0  = (const float*)d_in[1];
  const float* W_hh_l0  = (const float*)d_in[2];
  const float* b_ih_l0  = (const float*)d_in[3];
  const float* b_hh_l0  = (const float*)d_in[4];
  const float* W_ih_l0r = (const float*)d_in[5];
  const float* W_hh_l0r = (const float*)d_in[6];
  const float* b_ih_l0r = (const float*)d_in[7];
  const float* b_hh_l0r = (const float*)d_in[8];
  const float* W_ih_l1  = (const float*)d_in[9];
  const float* W_hh_l1  = (const float*)d_in[10];
  const float* b_ih_l1  = (const float*)d_in[11];
  const float* b_hh_l1  = (const float*)d_in[12];
  const float* W_ih_l1r = (const float*)d_in[13];
  const float* b_ih_l1r = (const float*)d_in[15];
  const float* b_hh_l1r = (const float*)d_in[16];
  const float* W_lin    = (const float*)d_in[17];
  const float* b_lin    = (const float*)d_in[18];

  float* y0f = (float*)d_ws;                        // 48 MB
  float* y0b = (float*)d_ws + (size_t)B_ * T_ * 3;  // 48 MB
  float* out = (float*)d_out;

  // K1: fwd stream (65536 threads) + bwd stream (65536) = 2048 waves (2/SIMD)
  lstm_l0_pair<<<(B_ * 8 * 2) / 256, 256, 0, stream>>>(
      x, W_ih_l0, W_hh_l0, b_ih_l0, b_hh_l0,
      W_ih_l0r, W_hh_l0r, b_ih_l0r, b_hh_l0r, y0f, y0b);

  // K2: 8 lanes/batch = 1024 waves
  lstm_l1_fwd<<<(B_ * 8) / 256, 256, 0, stream>>>(
      W_ih_l1, W_hh_l1, b_ih_l1, b_hh_l1,
      W_ih_l1r, b_ih_l1r, b_hh_l1r,
      W_lin, b_lin, y0f, y0b, out);
}